// Round 4
// baseline (1677.754 us; speedup 1.0000x reference)
//
#include <hip/hip_runtime.h>

#define D 1024
#define DT 0.1f

typedef __attribute__((ext_vector_type(8))) __bf16 bf16x8;
typedef __attribute__((ext_vector_type(4))) float floatx4;

__device__ __forceinline__ unsigned short f2bf(float f) {
  unsigned int u = __builtin_bit_cast(unsigned int, f);
  u = u + 0x7fffu + ((u >> 16) & 1u);           // RNE
  return (unsigned short)(u >> 16);
}
__device__ __forceinline__ float bf2f(unsigned short b) {
  return __builtin_bit_cast(float, ((unsigned int)b) << 16);
}

__device__ __forceinline__ void gload_lds16(const void* g, void* l) {
  __builtin_amdgcn_global_load_lds(
      (const __attribute__((address_space(1))) void*)g,
      (__attribute__((address_space(3))) void*)l, 16, 0, 0);
}

// tanh(x) = sign(x) * (1-e)/(1+e), e = exp(-2|x|)  — e in (0,1], no overflow.
__device__ __forceinline__ float fast_tanh(float x) {
  float ax = __builtin_fabsf(x);
  float e  = __expf(-2.0f * ax);
  float y  = (1.0f - e) * __builtin_amdgcn_rcpf(1.0f + e);
  return __builtin_copysignf(y, x);
}

// Split fp32 -> (hi, lo) bf16 pair; optionally copy the fp32 source (for traj[0]).
__global__ void __launch_bounds__(256) split_kernel(
    const float* __restrict__ src, float* __restrict__ copy_dst,
    unsigned short* __restrict__ hi, unsigned short* __restrict__ lo) {
  const int i = blockIdx.x * blockDim.x + threadIdx.x;   // one float4 / thread
  float4 v = ((const float4*)src)[i];
  if (copy_dst) ((float4*)copy_dst)[i] = v;
  ushort4 h, l;
  h.x = f2bf(v.x); l.x = f2bf(v.x - bf2f(h.x));
  h.y = f2bf(v.y); l.y = f2bf(v.y - bf2f(h.y));
  h.z = f2bf(v.z); l.z = f2bf(v.z - bf2f(h.z));
  h.w = f2bf(v.w); l.w = f2bf(v.w - bf2f(h.w));
  ((ushort4*)hi)[i] = h;
  ((ushort4*)lo)[i] = l;
}

// One Euler step: z = h @ W_k^T + b ; h' = h + DT*tanh(z)
// bf16x3 split precision: acc += Ah*Bh + Al*Bh + Ah*Bl.
//
// R4 structural change: 2 WORKGROUPS PER CU. 512 blocks x 256 threads (4
// waves), each block a 32x64 output tile (grid 32 rt x 16 ct). Per-CU MFMA
// and LDS-read totals are unchanged vs R1/R3; what changes is that the two
// co-resident blocks have INDEPENDENT barrier domains, so vmcnt waits,
// barriers, epilogue and ramp-down of one block overlap the other block's
// MFMA work. (R2 proved LDS BW not binding; R3 proved barrier count /
// prefetch depth not binding at 1 block/CU — the remaining suspect is
// whole-CU phase serialization, which TLP attacks directly.)
//
// Triple-buffered LDS (3 x 24 KiB = 72 KiB -> 2 blocks = 144 <= 160),
// single barrier per chunk (stage-after-barrier WAR scheme, R3-proven),
// counted vmcnt(6) keeps 2 chunks in flight, never drains mid-loop.
// XCD-aware 2D swizzle: per-XCD footprint A(1MB)+B(2MB) = 3MB < 4MB L2.
__global__ void __launch_bounds__(256, 2) step_kernel(
    const unsigned short* __restrict__ Ah, const unsigned short* __restrict__ Al,
    const unsigned short* __restrict__ Bh, const unsigned short* __restrict__ Bl,
    const float* __restrict__ bias,
    const float* __restrict__ hprev, float* __restrict__ hnext,
    unsigned short* __restrict__ Nh, unsigned short* __restrict__ Nl,
    float* __restrict__ feat) {
  __shared__ unsigned short lds[3 * 12288];   // 72 KiB: 3 bufs of sAh|sAl|sBh|sBl
  char* ldsb = (char*)lds;

  const int tid  = threadIdx.x;
  const int lane = tid & 63;
  const int wave = tid >> 6;       // 0..3
  const int wr   = wave >> 1;      // 0..1 (16-row block)
  const int wc   = wave & 1;       // 0..1 (32-col block)

  // ---- XCD-aware block -> (row-tile, col-tile). 512 blocks round-robin:
  // xcd = bid&7 owns rt in [8*(xcd>>1),+8), ct in [8*(xcd&1),+8);
  // its 64 blocks (j = bid>>3) fill that 8x8 tile region.
  const int xcd = blockIdx.x & 7;
  const int j8  = blockIdx.x >> 3;               // 0..63
  const int rt  = ((xcd >> 1) << 3) | (j8 >> 3); // 0..31
  const int ct  = ((xcd & 1) << 3) | (j8 & 7);   // 0..15
  const int row0 = rt << 5;                      // 32-row tile
  const int col0 = ct << 6;                      // 64-col tile

  const int quad = lane >> 4;
  const int l15  = lane & 15;
  const int x7   = lane & 7;

  // ---- staging addressing: each gload call stages 8 rows (1 KB).
  // LDS row = 128 B = 8 groups of 16 B; storage group g holds source
  // group g^(row&7); all staged row bases are multiples of 8 so row&7==srow.
  const int srow = lane >> 3;          // 0..7
  const int sgrp = x7 ^ srow;
  const long aoff = (long)(row0 + wave * 8 + srow) * D + sgrp * 8;   // A: 1 call/wave
  const long boff = (long)(col0 + wave * 16 + srow) * D + sgrp * 8;  // B: 2 calls/wave
  const unsigned short* gAh = Ah + aoff;
  const unsigned short* gAl = Al + aoff;
  const unsigned short* gBh = Bh + boff;
  const unsigned short* gBl = Bl + boff;
  const int swA = wave * 1024;         // A dest base within sA region
  const int swB = wave * 2048;         // B dest base within sB region

  // ---- epilogue prefetch: hprev + bias into registers before the K-loop ----
  const int ecol = col0 + (wc << 5) + l15;
  const int erow = row0 + (wr << 4) + (quad << 2);
  float hp0[4], hp1[4];
#pragma unroll
  for (int r = 0; r < 4; ++r) {
    const long i0 = (long)(erow + r) * D + ecol;
    hp0[r] = hprev[i0];
    hp1[r] = hprev[i0 + 16];
  }
  const float b0 = bias[ecol];
  const float b1 = bias[ecol + 16];

  // ---- fragment addressing ----
  const int Ra  = (wr << 4) | l15;     // A rows 0..31
  const int Rb0 = (wc << 5) | l15;     // B rows (C cols) 0..63
  const int Rb1 = Rb0 + 16;

  floatx4 acc0 = {0.f, 0.f, 0.f, 0.f};
  floatx4 acc1 = {0.f, 0.f, 0.f, 0.f};

  // buffer layout (24 KB): sAh [0,4K) sAl [4K,8K) sBh [8K,16K) sBl [16K,24K)
  auto stage = [&](int ck, int bo) {
    const int kk = ck << 6;
    gload_lds16(gAh + kk,         ldsb + bo + 0     + swA);
    gload_lds16(gAl + kk,         ldsb + bo + 4096  + swA);
    gload_lds16(gBh + kk,         ldsb + bo + 8192  + swB);
    gload_lds16(gBh + kk + 8 * D, ldsb + bo + 8192  + swB + 1024);
    gload_lds16(gBl + kk,         ldsb + bo + 16384 + swB);
    gload_lds16(gBl + kk + 8 * D, ldsb + bo + 16384 + swB + 1024);
  };

  // preload chunks 0,1 -> buffers 0,1 (2-deep lead)
  stage(0, 0);
  stage(1, 24576);

  int cur = 0;         // buffer holding chunk c        (24576 * cur)
  int nx  = 2;         // buffer receiving chunk c+2
  for (int c = 0; c < 16; ++c) {
    // wait for chunk c's 6 loads; keep chunk c+1's 6 in flight
    if (c <= 14) asm volatile("s_waitcnt vmcnt(6)" ::: "memory");
    else         asm volatile("s_waitcnt vmcnt(0)" ::: "memory");
    asm volatile("s_barrier" ::: "memory");   // data-arrival + WAR barrier
    // stage chunk c+2 into buffer (c+2)%3 == (c-1)%3 (its reads finished
    // before every wave arrived at the barrier above)
    if (c < 14) stage(c + 2, nx * 24576);
    const char* base = ldsb + cur * 24576;
#pragma unroll
    for (int kc = 0; kc < 2; ++kc) {
      const int gs = (((kc << 2) | quad) ^ x7) << 4;
      bf16x8 ah  = *(const bf16x8*)(base + 0     + Ra  * 128 + gs);
      bf16x8 al  = *(const bf16x8*)(base + 4096  + Ra  * 128 + gs);
      bf16x8 bh0 = *(const bf16x8*)(base + 8192  + Rb0 * 128 + gs);
      bf16x8 bl0 = *(const bf16x8*)(base + 16384 + Rb0 * 128 + gs);
      bf16x8 bh1 = *(const bf16x8*)(base + 8192  + Rb1 * 128 + gs);
      bf16x8 bl1 = *(const bf16x8*)(base + 16384 + Rb1 * 128 + gs);
      acc0 = __builtin_amdgcn_mfma_f32_16x16x32_bf16(ah, bh0, acc0, 0, 0, 0);
      acc1 = __builtin_amdgcn_mfma_f32_16x16x32_bf16(ah, bh1, acc1, 0, 0, 0);
      acc0 = __builtin_amdgcn_mfma_f32_16x16x32_bf16(al, bh0, acc0, 0, 0, 0);
      acc1 = __builtin_amdgcn_mfma_f32_16x16x32_bf16(al, bh1, acc1, 0, 0, 0);
      acc0 = __builtin_amdgcn_mfma_f32_16x16x32_bf16(ah, bl0, acc0, 0, 0, 0);
      acc1 = __builtin_amdgcn_mfma_f32_16x16x32_bf16(ah, bl1, acc1, 0, 0, 0);
    }
    cur = (cur == 2) ? 0 : cur + 1;
    nx  = (nx  == 2) ? 0 : nx  + 1;
  }

  // ---- epilogue: bias + tanh + Euler update; fp32 traj + bf16 hi/lo state ----
  const bool wf = (feat != nullptr);
#pragma unroll
  for (int r = 0; r < 4; ++r) {
    const long i0 = (long)(erow + r) * D + ecol;
    {
      float f  = fast_tanh(acc0[r] + b0);
      float hn = hp0[r] + DT * f;
      hnext[i0] = hn;
      unsigned short hb = f2bf(hn);
      Nh[i0] = hb;
      Nl[i0] = f2bf(hn - bf2f(hb));
      if (wf) feat[i0] = hn;
    }
    {
      const long i1 = i0 + 16;
      float f  = fast_tanh(acc1[r] + b1);
      float hn = hp1[r] + DT * f;
      hnext[i1] = hn;
      unsigned short hb = f2bf(hn);
      Nh[i1] = hb;
      Nl[i1] = f2bf(hn - bf2f(hb));
      if (wf) feat[i1] = hn;
    }
  }
}

extern "C" void kernel_launch(void* const* d_in, const int* in_sizes, int n_in,
                              void* d_out, int out_size, void* d_ws, size_t ws_size,
                              hipStream_t stream) {
  const float* x = (const float*)d_in[0];
  const float* W = (const float*)d_in[1];
  const float* b = (const float*)d_in[2];
  float* out  = (float*)d_out;
  float* feat = out;                       // [1024,1024] final features
  float* traj = out + (size_t)D * D;       // [101,1024,1024]

  const size_t M = (size_t)D * D;          // 1M elements
  unsigned short* ws = (unsigned short*)d_ws;
  const int splitBlocks = (int)(M / 4 / 256);   // 1024

  const bool big = ws_size >= (size_t)48 * 1024 * 1024;

  if (big) {
    // layout: Whi[10*M] | Wlo[10*M] | h hi/lo double buffers [4*M]  = 48 MB
    unsigned short* wh_all = ws;
    unsigned short* wl_all = wh_all + 10 * M;
    unsigned short* hbuf   = wl_all + 10 * M;
    unsigned short* hh[2] = {hbuf, hbuf + 2 * M};
    unsigned short* hl[2] = {hbuf + M, hbuf + 3 * M};

    // convert all 10 W slabs up-front (one launch), and seed h state + traj[0]
    split_kernel<<<splitBlocks * 10, 256, 0, stream>>>(W, (float*)nullptr, wh_all, wl_all);
    split_kernel<<<splitBlocks, 256, 0, stream>>>(x, traj, hh[0], hl[0]);

    for (int n = 0; n < 100; ++n) {
      const int k = n / 10;
      step_kernel<<<512, 256, 0, stream>>>(
          hh[n & 1], hl[n & 1], wh_all + (size_t)k * M, wl_all + (size_t)k * M,
          b + (size_t)k * D,
          traj + (size_t)n * M, traj + (size_t)(n + 1) * M,
          hh[(n + 1) & 1], hl[(n + 1) & 1],
          (n == 99) ? feat : nullptr);
    }
  } else {
    // fallback: per-slab W conversion (12 MB ws)
    unsigned short* wh    = ws;
    unsigned short* wl    = wh + M;
    unsigned short* hbuf  = wl + M;
    unsigned short* hh[2] = {hbuf, hbuf + 2 * M};
    unsigned short* hl[2] = {hbuf + M, hbuf + 3 * M};

    split_kernel<<<splitBlocks, 256, 0, stream>>>(x, traj, hh[0], hl[0]);
    for (int k = 0; k < 10; ++k) {
      split_kernel<<<splitBlocks, 256, 0, stream>>>(W + k * M, (float*)nullptr, wh, wl);
      for (int s = 0; s < 10; ++s) {
        const int n = k * 10 + s;
        step_kernel<<<512, 256, 0, stream>>>(
            hh[n & 1], hl[n & 1], wh, wl, b + (size_t)k * D,
            traj + (size_t)n * M, traj + (size_t)(n + 1) * M,
            hh[(n + 1) & 1], hl[(n + 1) & 1],
            (n == 99) ? feat : nullptr);
      }
    }
  }
}